// Round 10
// baseline (238.673 us; speedup 1.0000x reference)
//
#include <hip/hip_runtime.h>
#include <math.h>

#define DM   1024
#define SL   2048
#define NB   2
#define NH   16
#define DKH  64
#define DFF  4096
#define NTOK 4096

typedef unsigned short u16;
typedef unsigned int u32;
typedef __attribute__((ext_vector_type(8))) short bf16x8;
typedef __attribute__((ext_vector_type(4))) float f32x4;
typedef __attribute__((ext_vector_type(16))) float f32x16;

typedef __attribute__((address_space(1))) void gvoid;
typedef __attribute__((address_space(3))) void lvoid;

// Q projection scale: (1/sqrt(64)) * log2(e)  -> softmax in exp2 domain
#define QSCALE 0.18033688011112042f

__device__ __forceinline__ u16 f2bf(float f) {
  union { float f; unsigned u; } v; v.f = f;
  unsigned r = (v.u + 0x7fffu + ((v.u >> 16) & 1u)) >> 16;
  return (u16)r;
}
__device__ __forceinline__ float bf2f(u16 h) {
  union { unsigned u; float f; } v; v.u = ((unsigned)h) << 16; return v.f;
}
__device__ __forceinline__ void gld16(const u16* g, u16* l) {
  __builtin_amdgcn_global_load_lds((gvoid*)g, (lvoid*)l, 16, 0, 0);
}

// ---------------- fp32 -> bf16 conversion of x + all weights (one kernel) ---
__global__ __launch_bounds__(256)
void cvt_all(const float* __restrict__ x,  const float* __restrict__ wq,
             const float* __restrict__ wk, const float* __restrict__ wv,
             const float* __restrict__ wo, const float* __restrict__ w1,
             const float* __restrict__ w2,
             u16* __restrict__ xb, u16* __restrict__ wqb, u16* __restrict__ wkb,
             u16* __restrict__ wvb, u16* __restrict__ wob, u16* __restrict__ w1b,
             u16* __restrict__ w2b) {
  const int total = 4194304;  // float4 units
  for (int i = blockIdx.x * blockDim.x + threadIdx.x; i < total;
       i += gridDim.x * blockDim.x) {
    const float* src; u16* dst; int off;
    if      (i < 1048576) { src = x;  dst = xb;  off = i; }
    else if (i < 1310720) { src = wq; dst = wqb; off = i - 1048576; }
    else if (i < 1572864) { src = wk; dst = wkb; off = i - 1310720; }
    else if (i < 1835008) { src = wv; dst = wvb; off = i - 1572864; }
    else if (i < 2097152) { src = wo; dst = wob; off = i - 1835008; }
    else if (i < 3145728) { src = w1; dst = w1b; off = i - 2097152; }
    else                  { src = w2; dst = w2b; off = i - 3145728; }
    float4 v = ((const float4*)src)[off];
    ushort4 o = { f2bf(v.x), f2bf(v.y), f2bf(v.z), f2bf(v.w) };
    ((ushort4*)dst)[off] = o;
  }
}

// ---------------- GEMM: C[M,N] = A[M,K] @ W[N,K]^T + bias, fused epilogues --
// R8 schedule (dbuf 2-phase), inner loop on 32x32x16 MFMA (half the MFMA
// instructions, 2382 vs 2075 TF rate; ds_read count/bytes unchanged).
// EPI: 3=O(bf16 out, + bf16 resid)  4=FF1(bf16, gelu)  5=FF2(bf16, + bf16 resid)
#define BM 128
#define BN 128
#define BK 64

template <int EPI>
__global__ __launch_bounds__(256, 2)
void gemm_bt(const u16* __restrict__ A, const u16* __restrict__ W,
             const float* __restrict__ bias, const u16* __restrict__ residb,
             void* __restrict__ out, int M, int N, int K) {
  __shared__ u16 smem[2][2][BM * BK];  // 64 KiB
  const int tid = threadIdx.x;
  const int lane = tid & 63;
  const int wid  = tid >> 6;
  const int l31  = lane & 31;
  const int h    = lane >> 5;
  const int wm = wid >> 1, wn = wid & 1;
  const int bm = blockIdx.x * BM;
  const int bn = blockIdx.y * BN;

  const int srow  = tid >> 3;
  const int sslot = (tid & 7) ^ (srow & 7);
  const size_t aoff = (size_t)(bm + srow) * K + sslot * 8;
  const size_t boff = (size_t)(bn + srow) * K + sslot * 8;

  f32x16 acc[2][2] = {};
  const int nk = K / BK;
  int cur = 0;

  auto STAGE = [&](int buf, int kt) {
    const u16* ga = A + aoff + kt * BK;
    const u16* gb = W + boff + kt * BK;
    u16* la = &smem[buf][0][wid * 512];
    u16* lb = &smem[buf][1][wid * 512];
#pragma unroll
    for (int i = 0; i < 4; ++i) {
      gld16(ga + (size_t)i * 32 * K, la + i * 2048);
      gld16(gb + (size_t)i * 32 * K, lb + i * 2048);
    }
  };

  STAGE(0, 0);
  __syncthreads();

  for (int kt = 0; kt < nk; ++kt) {
    if (kt + 1 < nk) STAGE(cur ^ 1, kt + 1);
    const u16* la = &smem[cur][0][0];
    const u16* lb = &smem[cur][1][0];
#pragma unroll
    for (int ks = 0; ks < 4; ++ks) {
      bf16x8 af[2], bfr[2];
#pragma unroll
      for (int mi = 0; mi < 2; ++mi) {
        const int row = wm * 64 + mi * 32 + l31;
        af[mi] = *(const bf16x8*)&la[row * 64 + (((ks * 2 + h) ^ (row & 7)) * 8)];
      }
#pragma unroll
      for (int nj = 0; nj < 2; ++nj) {
        const int row = wn * 64 + nj * 32 + l31;
        bfr[nj] = *(const bf16x8*)&lb[row * 64 + (((ks * 2 + h) ^ (row & 7)) * 8)];
      }
      __builtin_amdgcn_s_setprio(1);
#pragma unroll
      for (int mi = 0; mi < 2; ++mi)
#pragma unroll
        for (int nj = 0; nj < 2; ++nj)
          acc[mi][nj] = __builtin_amdgcn_mfma_f32_32x32x16_bf16(
              af[mi], bfr[nj], acc[mi][nj], 0, 0, 0);
      __builtin_amdgcn_s_setprio(0);
    }
    __syncthreads();
    cur ^= 1;
  }

  // epilogue; 32x32 C/D layout: col = lane&31, row = (reg&3)+8*(reg>>2)+4*h
#pragma unroll
  for (int mi = 0; mi < 2; ++mi) {
#pragma unroll
    for (int nj = 0; nj < 2; ++nj) {
      const int c = bn + wn * 64 + nj * 32 + l31;
      const float bv = bias[c];
#pragma unroll
      for (int reg = 0; reg < 16; ++reg) {
        const int r = bm + wm * 64 + mi * 32 + (reg & 3) + 8 * (reg >> 2) + 4 * h;
        float v = acc[mi][nj][reg] + bv;
        if (EPI == 4) {
          const float gl = 0.5f * v * (1.0f + erff(v * 0.7071067811865475f));
          ((u16*)out)[(size_t)r * N + c] = f2bf(gl);
        } else {
          ((u16*)out)[(size_t)r * N + c] =
              f2bf(v + bf2f(residb[(size_t)r * N + c]));
        }
      }
    }
  }
}

// ---------------- fused QKV GEMM (768 blocks, R8-exact) ---------------------
__global__ __launch_bounds__(256, 2)
void gemm_qkv(const u16* __restrict__ A, const u16* __restrict__ wq,
              const u16* __restrict__ wk, const u16* __restrict__ wv,
              const float* __restrict__ bq, const float* __restrict__ bk,
              const float* __restrict__ bv,
              u16* __restrict__ qo, u16* __restrict__ ko, u16* __restrict__ vo) {
  __shared__ u16 smem[2][2][BM * BK];
  const int tid = threadIdx.x;
  const int lane = tid & 63;
  const int wid  = tid >> 6;
  const int r16  = lane & 15;
  const int hi   = lane >> 4;
  const int wm = wid >> 1, wn = wid & 1;
  const int bm = blockIdx.x * BM;
  const int sel = blockIdx.y >> 3;           // 0=Q 1=K 2=V
  const int bn  = (blockIdx.y & 7) * BN;
  const u16* W = sel == 0 ? wq : sel == 1 ? wk : wv;
  const float* bias = sel == 0 ? bq : sel == 1 ? bk : bv;
  const int K = DM, N = DM;

  const int srow  = tid >> 3;
  const int sslot = (tid & 7) ^ (srow & 7);
  const size_t aoff = (size_t)(bm + srow) * K + sslot * 8;
  const size_t boff = (size_t)(bn + srow) * K + sslot * 8;

  f32x4 acc[4][4] = {};
  int cur = 0;

  auto STAGE = [&](int buf, int kt) {
    const u16* ga = A + aoff + kt * BK;
    const u16* gb = W + boff + kt * BK;
    u16* la = &smem[buf][0][wid * 512];
    u16* lb = &smem[buf][1][wid * 512];
#pragma unroll
    for (int i = 0; i < 4; ++i) {
      gld16(ga + (size_t)i * 32 * K, la + i * 2048);
      gld16(gb + (size_t)i * 32 * K, lb + i * 2048);
    }
  };

  STAGE(0, 0);
  __syncthreads();

  for (int kt = 0; kt < 16; ++kt) {
    if (kt + 1 < 16) STAGE(cur ^ 1, kt + 1);
    const u16* la = &smem[cur][0][0];
    const u16* lb = &smem[cur][1][0];
#pragma unroll
    for (int kk = 0; kk < 2; ++kk) {
      const int swz = ((kk * 4 + hi) ^ (r16 & 7)) * 8;
      bf16x8 af[4], bfr[4];
#pragma unroll
      for (int i = 0; i < 4; ++i)
        af[i] = *(const bf16x8*)&la[(wm * 64 + i * 16 + r16) * 64 + swz];
#pragma unroll
      for (int j = 0; j < 4; ++j)
        bfr[j] = *(const bf16x8*)&lb[(wn * 64 + j * 16 + r16) * 64 + swz];
      __builtin_amdgcn_s_setprio(1);
#pragma unroll
      for (int i = 0; i < 4; ++i)
#pragma unroll
        for (int j = 0; j < 4; ++j)
          acc[i][j] = __builtin_amdgcn_mfma_f32_16x16x32_bf16(af[i], bfr[j],
                                                              acc[i][j], 0, 0, 0);
      __builtin_amdgcn_s_setprio(0);
    }
    __syncthreads();
    cur ^= 1;
  }

#pragma unroll
  for (int i = 0; i < 4; ++i) {
#pragma unroll
    for (int j = 0; j < 4; ++j) {
      const int c  = bn + wn * 64 + j * 16 + r16;
      const int r0 = bm + wm * 64 + i * 16 + hi * 4;
      const float bvv = bias[c];
#pragma unroll
      for (int rr = 0; rr < 4; ++rr) {
        const int r = r0 + rr;
        const float v = acc[i][j][rr] + bvv;
        if (sel == 0) {
          qo[(size_t)r * N + c] = f2bf(v * QSCALE);
        } else if (sel == 1) {
          ko[(size_t)r * N + c] = f2bf(v);
        } else {
          const int b = r >> 11, s = r & 2047;
          const int hh = c >> 6, dk = c & 63;
          vo[((size_t)((b * NH + hh) * DKH + dk)) * SL + s] = f2bf(v);
        }
      }
    }
  }
}

// ---------------- flash attention, swapped-operand 32x32 MFMA (R8-exact) ----
__global__ __launch_bounds__(256, 2)
void attn(const u16* __restrict__ q, const u16* __restrict__ k,
          const u16* __restrict__ vt, u16* __restrict__ ctx) {
  __shared__ u16 kl[2][64 * 64];   // [kv][dk] swizzled
  __shared__ u16 vl[2][64 * 64];   // [dk][kv] swizzled

  const int tid = threadIdx.x;
  const int lane = tid & 63, wid = tid >> 6;
  const int l31 = lane & 31, h = lane >> 5;
  const int rs = l31 & 7;
  const int bh = blockIdx.x, b = bh >> 4, hh = bh & 15;
  const int qg = blockIdx.y * 128 + wid * 32 + l31;   // this lane's q row

  bf16x8 qf[4];
#pragma unroll
  for (int kq = 0; kq < 4; ++kq)
    qf[kq] = *(const bf16x8*)(q + (size_t)(b * SL + qg) * DM + hh * DKH +
                              kq * 16 + h * 8);

  f32x16 o0 = {}, o1 = {};          // O^T accum: dk rows [0,32) and [32,64)
  float mrun = -1e30f, lrun = 0.f;

  const int srow  = tid >> 3;
  const int sslot = (tid & 7) ^ (srow & 7);

  auto STAGE = [&](int buf, int t) {
    const u16* gk = k + (size_t)(b * SL + t * 64 + srow) * DM + hh * DKH + sslot * 8;
    const u16* gv = vt + (size_t)(bh * DKH + srow) * SL + t * 64 + sslot * 8;
    u16* lk = &kl[buf][wid * 512];
    u16* lv = &vl[buf][wid * 512];
#pragma unroll
    for (int i = 0; i < 2; ++i) {
      gld16(gk + (size_t)i * 32 * DM, lk + i * 2048);
      gld16(gv + (size_t)i * 32 * SL, lv + i * 2048);
    }
  };

  auto TILE = [&](int buf) {
    const u16* lk = kl[buf];
    const u16* lv = vl[buf];
    f32x16 s0 = {}, s1 = {};   // S^T fragments: kv rows [0,32) and [32,64)
    __builtin_amdgcn_s_setprio(1);
#pragma unroll
    for (int kq = 0; kq < 4; ++kq) {
      const int ls = 2 * kq + h;
      bf16x8 k0 = *(const bf16x8*)&lk[l31 * 64 + ((ls ^ rs) * 8)];
      bf16x8 k1 = *(const bf16x8*)&lk[(l31 + 32) * 64 + ((ls ^ rs) * 8)];
      s0 = __builtin_amdgcn_mfma_f32_32x32x16_bf16(k0, qf[kq], s0, 0, 0, 0);
      s1 = __builtin_amdgcn_mfma_f32_32x32x16_bf16(k1, qf[kq], s1, 0, 0, 0);
    }
    __builtin_amdgcn_s_setprio(0);

    float mx = fmaxf(s0[0], s0[1]);
#pragma unroll
    for (int r = 2; r < 16; ++r) mx = fmaxf(mx, s0[r]);
#pragma unroll
    for (int r = 0; r < 16; ++r) mx = fmaxf(mx, s1[r]);
    {
      float ta = mx, tb = mx;
      asm volatile("v_permlane32_swap_b32 %0, %1" : "+v"(ta), "+v"(tb));
      mx = fmaxf(ta, tb);
    }
    if (!__all(mx <= mrun + 11.0f)) {
      const float mn = fmaxf(mrun, mx);
      const float al = __builtin_amdgcn_exp2f(mrun - mn);
      mrun = mn;
      lrun *= al;
      o0 *= al; o1 *= al;
    }
    float lsum = 0.f;
#pragma unroll
    for (int r = 0; r < 16; ++r) {
      s0[r] = __builtin_amdgcn_exp2f(s0[r] - mrun); lsum += s0[r];
    }
#pragma unroll
    for (int r = 0; r < 16; ++r) {
      s1[r] = __builtin_amdgcn_exp2f(s1[r] - mrun); lsum += s1[r];
    }
    lrun += lsum;

    u32 A[16];
#pragma unroll
    for (int r = 0; r < 8; ++r)
      asm("v_cvt_pk_bf16_f32 %0, %1, %2"
          : "=v"(A[r]) : "v"(s0[2 * r]), "v"(s0[2 * r + 1]));
#pragma unroll
    for (int r = 0; r < 8; ++r)
      asm("v_cvt_pk_bf16_f32 %0, %1, %2"
          : "=v"(A[8 + r]) : "v"(s1[2 * r]), "v"(s1[2 * r + 1]));
#pragma unroll
    for (int g = 0; g < 4; ++g) {
      asm volatile("v_permlane32_swap_b32 %0, %1" : "+v"(A[4 * g + 0]), "+v"(A[4 * g + 2]));
      asm volatile("v_permlane32_swap_b32 %0, %1" : "+v"(A[4 * g + 1]), "+v"(A[4 * g + 3]));
    }

    __builtin_amdgcn_s_setprio(1);
#pragma unroll
    for (int ks = 0; ks < 4; ++ks) {
      union { u32 u[4]; bf16x8 hv; } pb;
      pb.u[0] = A[4 * ks + 0]; pb.u[1] = A[4 * ks + 1];
      pb.u[2] = A[4 * ks + 2]; pb.u[3] = A[4 * ks + 3];
      const int ls = 2 * ks + h;
      bf16x8 v0 = *(const bf16x8*)&lv[l31 * 64 + ((ls ^ rs) * 8)];
      bf16x8 v1 = *(const bf16x8*)&lv[(l31 + 32) * 64 + ((ls ^ rs) * 8)];
      o0 = __builtin_amdgcn_mfma_f32_32x32x16_bf16(v0, pb.hv, o0, 0, 0, 0);
      o1 = __builtin_amdgcn_mfma_f32_32x32x16_bf16(v1, pb.hv, o1, 0, 0, 0);
    }
    __builtin_amdgcn_s_setprio(0);
  };

  STAGE(0, 0);
  __syncthreads();
  int cur = 0;
  for (int t = 0; t < SL / 64; ++t) {
    if (t + 1 < SL / 64) STAGE(cur ^ 1, t + 1);
    TILE(cur);
    __syncthreads();
    cur ^= 1;
  }

  float ta = lrun, tb = lrun;
  asm volatile("v_permlane32_swap_b32 %0, %1" : "+v"(ta), "+v"(tb));
  const float rl = 1.f / (ta + tb);
  const size_t obase = (size_t)(b * SL + qg) * DM + hh * DKH;
#pragma unroll
  for (int df = 0; df < 2; ++df) {
#pragma unroll
    for (int r2 = 0; r2 < 4; ++r2) {
      const int dk0 = 8 * r2 + 4 * h + 32 * df;
      ushort4 st;
      if (df == 0) {
        st.x = f2bf(o0[4 * r2 + 0] * rl); st.y = f2bf(o0[4 * r2 + 1] * rl);
        st.z = f2bf(o0[4 * r2 + 2] * rl); st.w = f2bf(o0[4 * r2 + 3] * rl);
      } else {
        st.x = f2bf(o1[4 * r2 + 0] * rl); st.y = f2bf(o1[4 * r2 + 1] * rl);
        st.z = f2bf(o1[4 * r2 + 2] * rl); st.w = f2bf(o1[4 * r2 + 3] * rl);
      }
      *(ushort4*)(ctx + obase + dk0) = st;
    }
  }
}

// ---------------- LayerNorm over last dim (1024), one block per row ---------
// INBF: input dtype bf16 (1) or f32 (0); outputs: f32 (outf) and/or bf16 (outb)
template <int INBF>
__global__ __launch_bounds__(256)
void ln_k(const void* __restrict__ inp, const float* __restrict__ g,
          const float* __restrict__ be, float* __restrict__ outf,
          u16* __restrict__ outb) {
  const int row = blockIdx.x;
  const int tid = threadIdx.x;
  float4 x4;
  if (INBF) {
    ushort4 h4 = ((const ushort4*)((const u16*)inp + (size_t)row * DM))[tid];
    x4.x = bf2f(h4.x); x4.y = bf2f(h4.y); x4.z = bf2f(h4.z); x4.w = bf2f(h4.w);
  } else {
    x4 = ((const float4*)((const float*)inp + (size_t)row * DM))[tid];
  }
  float s  = x4.x + x4.y + x4.z + x4.w;
  float s2 = x4.x * x4.x + x4.y * x4.y + x4.z * x4.z + x4.w * x4.w;
#pragma unroll
  for (int d = 1; d < 64; d <<= 1) {
    s  += __shfl_xor(s, d);
    s2 += __shfl_xor(s2, d);
  }
  __shared__ float ps[8];
  const int wid = tid >> 6, lane = tid & 63;
  if (lane == 0) { ps[wid] = s; ps[wid + 4] = s2; }
  __syncthreads();
  const float S  = ps[0] + ps[1] + ps[2] + ps[3];
  const float S2 = ps[4] + ps[5] + ps[6] + ps[7];
  const float mu = S * (1.f / DM);
  const float var = S2 * (1.f / DM) - mu * mu;
  const float rstd = 1.f / sqrtf(var + 1e-5f);
  const float4 gv = ((const float4*)g)[tid];
  const float4 bv = ((const float4*)be)[tid];
  float4 o;
  o.x = (x4.x - mu) * rstd * gv.x + bv.x;
  o.y = (x4.y - mu) * rstd * gv.y + bv.y;
  o.z = (x4.z - mu) * rstd * gv.z + bv.z;
  o.w = (x4.w - mu) * rstd * gv.w + bv.w;
  if (outf) ((float4*)(outf + (size_t)row * DM))[tid] = o;
  if (outb) {
    ushort4 ob = { f2bf(o.x), f2bf(o.y), f2bf(o.z), f2bf(o.w) };
    ((ushort4*)(outb + (size_t)row * DM))[tid] = ob;
  }
}

// ---------------------------------------------------------------------------
extern "C" void kernel_launch(void* const* d_in, const int* in_sizes, int n_in,
                              void* d_out, int out_size, void* d_ws, size_t ws_size,
                              hipStream_t stream) {
  const float* x   = (const float*)d_in[0];
  const float* wq  = (const float*)d_in[1];
  const float* bq  = (const float*)d_in[2];
  const float* wk  = (const float*)d_in[3];
  const float* bk  = (const float*)d_in[4];
  const float* wv  = (const float*)d_in[5];
  const float* bv  = (const float*)d_in[6];
  const float* wo  = (const float*)d_in[7];
  const float* bo  = (const float*)d_in[8];
  const float* g1  = (const float*)d_in[9];
  const float* be1 = (const float*)d_in[10];
  const float* w1  = (const float*)d_in[11];
  const float* b1  = (const float*)d_in[12];
  const float* w2  = (const float*)d_in[13];
  const float* b2  = (const float*)d_in[14];
  const float* g2  = (const float*)d_in[15];
  const float* be2 = (const float*)d_in[16];

  if (ws_size < ((size_t)80 << 20)) return;  // need 80 MiB of scratch

  char* ws = (char*)d_ws;
  u16*  xb   = (u16*)(ws);                      // 8M  [0,8)
  u16*  wqb  = (u16*)(ws + ((size_t)8  << 20)); // 2M
  u16*  wkb  = (u16*)(ws + ((size_t)10 << 20));
  u16*  wvb  = (u16*)(ws + ((size_t)12 << 20));
  u16*  wob  = (u16*)(ws + ((size_t)14 << 20));
  u16*  w1b  = (u16*)(ws + ((size_t)16 << 20)); // 8M
  u16*  w2b  = (u16*)(ws + ((size_t)24 << 20)); // 8M
  u16*  qbuf = (u16*)(ws + ((size_t)32 << 20)); // 8M
  u16*  kbuf = (u16*)(ws + ((size_t)40 << 20)); // 8M
  u16*  vtb  = (u16*)(ws + ((size_t)48 << 20)); // 8M
  u16*  ctx  = (u16*)(ws + ((size_t)56 << 20)); // 8M
  u16*  oresb = (u16*)(ws + ((size_t)64 << 20)); // 8M bf16 (o-proj + x)
  u16*  ffb   = (u16*)(ws + ((size_t)72 << 20)); // 8M bf16 (ff2 + attn_out)
  u16*  aob  = xb;    // alias: attn_out bf16 over xb (dead after QKV+O-proj)
  u16*  hb   = qbuf;  // alias: FFN hidden (32M) over q/k/vt/ctx (dead)

  float* out = (float*)d_out;
  dim3 blk(256);

  cvt_all<<<2048, blk, 0, stream>>>(x, wq, wk, wv, wo, w1, w2,
                                    xb, wqb, wkb, wvb, wob, w1b, w2b);
  gemm_qkv<<<dim3(32, 24), blk, 0, stream>>>(xb, wqb, wkb, wvb, bq, bk, bv,
                                             qbuf, kbuf, vtb);
  attn<<<dim3(32, 16), blk, 0, stream>>>(qbuf, kbuf, vtb, ctx);
  // O-proj residual reads bf16 xb (x already rounded once for projections)
  gemm_bt<3><<<dim3(32, 8), blk, 0, stream>>>(ctx, wob, bo, xb, oresb,
                                              NTOK, DM, DM);
  ln_k<1><<<4096, blk, 0, stream>>>(oresb, g1, be1, nullptr, aob);
  gemm_bt<4><<<dim3(32, 32), blk, 0, stream>>>(aob, w1b, b1, nullptr,
                                               hb, NTOK, DFF, DM);
  gemm_bt<5><<<dim3(32, 8), blk, 0, stream>>>(hb, w2b, b2, aob, ffb,
                                              NTOK, DM, DFF);
  ln_k<1><<<4096, blk, 0, stream>>>(ffb, g2, be2, out, nullptr);
}

// Round 11
// 225.836 us; speedup vs baseline: 1.0568x; 1.0568x over previous
//
#include <hip/hip_runtime.h>
#include <math.h>

#define DM   1024
#define SL   2048
#define NB   2
#define NH   16
#define DKH  64
#define DFF  4096
#define NTOK 4096

typedef unsigned short u16;
typedef unsigned int u32;
typedef __attribute__((ext_vector_type(8))) short bf16x8;
typedef __attribute__((ext_vector_type(4))) float f32x4;
typedef __attribute__((ext_vector_type(16))) float f32x16;

typedef __attribute__((address_space(1))) void gvoid;
typedef __attribute__((address_space(3))) void lvoid;

// Q projection scale: (1/sqrt(64)) * log2(e)  -> softmax in exp2 domain
#define QSCALE 0.18033688011112042f

__device__ __forceinline__ u16 f2bf(float f) {
  union { float f; unsigned u; } v; v.f = f;
  unsigned r = (v.u + 0x7fffu + ((v.u >> 16) & 1u)) >> 16;
  return (u16)r;
}
__device__ __forceinline__ float bf2f(u16 h) {
  union { unsigned u; float f; } v; v.u = ((unsigned)h) << 16; return v.f;
}
__device__ __forceinline__ void gld16(const u16* g, u16* l) {
  __builtin_amdgcn_global_load_lds((gvoid*)g, (lvoid*)l, 16, 0, 0);
}
// tanh-form GELU via exp2 (|err vs erf-gelu| <= ~3e-3, fine for bf16 out)
__device__ __forceinline__ float gelu_fast(float v) {
  const float u = 2.302208f * (v + 0.044715f * v * v * v);  // 2*0.7978845*log2e
  const float e = __builtin_amdgcn_exp2f(u);
  return v - v * __builtin_amdgcn_rcpf(e + 1.0f);           // 0.5v(1+tanh)
}

// ---------------- fp32 -> bf16 conversion of x + all weights (one kernel) ---
__global__ __launch_bounds__(256)
void cvt_all(const float* __restrict__ x,  const float* __restrict__ wq,
             const float* __restrict__ wk, const float* __restrict__ wv,
             const float* __restrict__ wo, const float* __restrict__ w1,
             const float* __restrict__ w2,
             u16* __restrict__ xb, u16* __restrict__ wqb, u16* __restrict__ wkb,
             u16* __restrict__ wvb, u16* __restrict__ wob, u16* __restrict__ w1b,
             u16* __restrict__ w2b) {
  const int total = 4194304;  // float4 units
  for (int i = blockIdx.x * blockDim.x + threadIdx.x; i < total;
       i += gridDim.x * blockDim.x) {
    const float* src; u16* dst; int off;
    if      (i < 1048576) { src = x;  dst = xb;  off = i; }
    else if (i < 1310720) { src = wq; dst = wqb; off = i - 1048576; }
    else if (i < 1572864) { src = wk; dst = wkb; off = i - 1310720; }
    else if (i < 1835008) { src = wv; dst = wvb; off = i - 1572864; }
    else if (i < 2097152) { src = wo; dst = wob; off = i - 1835008; }
    else if (i < 3145728) { src = w1; dst = w1b; off = i - 2097152; }
    else                  { src = w2; dst = w2b; off = i - 3145728; }
    float4 v = ((const float4*)src)[off];
    ushort4 o = { f2bf(v.x), f2bf(v.y), f2bf(v.z), f2bf(v.w) };
    ((ushort4*)dst)[off] = o;
  }
}

// ---------------- GEMM: C[M,N] = A[M,K] @ W[N,K]^T + bias (R8-exact loop) ---
// EPI: 3 = add bf16 residual -> bf16 out   4 = fast GELU -> bf16 out
#define BM 128
#define BN 128
#define BK 64

template <int EPI>
__global__ __launch_bounds__(256, 2)
void gemm_bt(const u16* __restrict__ A, const u16* __restrict__ W,
             const float* __restrict__ bias, const u16* __restrict__ residb,
             void* __restrict__ out, int M, int N, int K) {
  __shared__ u16 smem[2][2][BM * BK];  // 64 KiB
  const int tid = threadIdx.x;
  const int lane = tid & 63;
  const int wid  = tid >> 6;
  const int r16  = lane & 15;
  const int hi   = lane >> 4;
  const int wm = wid >> 1, wn = wid & 1;
  const int bm = blockIdx.x * BM;
  const int bn = blockIdx.y * BN;

  const int srow  = tid >> 3;
  const int sslot = (tid & 7) ^ (srow & 7);
  const size_t aoff = (size_t)(bm + srow) * K + sslot * 8;
  const size_t boff = (size_t)(bn + srow) * K + sslot * 8;

  f32x4 acc[4][4] = {};
  const int nk = K / BK;
  int cur = 0;

  auto STAGE = [&](int buf, int kt) {
    const u16* ga = A + aoff + kt * BK;
    const u16* gb = W + boff + kt * BK;
    u16* la = &smem[buf][0][wid * 512];
    u16* lb = &smem[buf][1][wid * 512];
#pragma unroll
    for (int i = 0; i < 4; ++i) {
      gld16(ga + (size_t)i * 32 * K, la + i * 2048);
      gld16(gb + (size_t)i * 32 * K, lb + i * 2048);
    }
  };

  STAGE(0, 0);
  __syncthreads();

  for (int kt = 0; kt < nk; ++kt) {
    if (kt + 1 < nk) STAGE(cur ^ 1, kt + 1);
    const u16* la = &smem[cur][0][0];
    const u16* lb = &smem[cur][1][0];
#pragma unroll
    for (int kk = 0; kk < 2; ++kk) {
      const int swz = ((kk * 4 + hi) ^ (r16 & 7)) * 8;
      bf16x8 af[4], bfr[4];
#pragma unroll
      for (int i = 0; i < 4; ++i)
        af[i] = *(const bf16x8*)&la[(wm * 64 + i * 16 + r16) * 64 + swz];
#pragma unroll
      for (int j = 0; j < 4; ++j)
        bfr[j] = *(const bf16x8*)&lb[(wn * 64 + j * 16 + r16) * 64 + swz];
      __builtin_amdgcn_s_setprio(1);
#pragma unroll
      for (int i = 0; i < 4; ++i)
#pragma unroll
        for (int j = 0; j < 4; ++j)
          acc[i][j] = __builtin_amdgcn_mfma_f32_16x16x32_bf16(af[i], bfr[j],
                                                              acc[i][j], 0, 0, 0);
      __builtin_amdgcn_s_setprio(0);
    }
    __syncthreads();
    cur ^= 1;
  }

#pragma unroll
  for (int i = 0; i < 4; ++i) {
#pragma unroll
    for (int j = 0; j < 4; ++j) {
      const int c  = bn + wn * 64 + j * 16 + r16;
      const int r0 = bm + wm * 64 + i * 16 + hi * 4;
      const float bv = bias[c];
#pragma unroll
      for (int rr = 0; rr < 4; ++rr) {
        const int r = r0 + rr;
        float v = acc[i][j][rr] + bv;
        if (EPI == 3) {
          ((u16*)out)[(size_t)r * N + c] =
              f2bf(v + bf2f(residb[(size_t)r * N + c]));
        } else {
          ((u16*)out)[(size_t)r * N + c] = f2bf(gelu_fast(v));
        }
      }
    }
  }
}

// ---------------- fused QKV GEMM (768 blocks, R8-exact) ---------------------
__global__ __launch_bounds__(256, 2)
void gemm_qkv(const u16* __restrict__ A, const u16* __restrict__ wq,
              const u16* __restrict__ wk, const u16* __restrict__ wv,
              const float* __restrict__ bq, const float* __restrict__ bk,
              const float* __restrict__ bv,
              u16* __restrict__ qo, u16* __restrict__ ko, u16* __restrict__ vo) {
  __shared__ u16 smem[2][2][BM * BK];
  const int tid = threadIdx.x;
  const int lane = tid & 63;
  const int wid  = tid >> 6;
  const int r16  = lane & 15;
  const int hi   = lane >> 4;
  const int wm = wid >> 1, wn = wid & 1;
  const int bm = blockIdx.x * BM;
  const int sel = blockIdx.y >> 3;           // 0=Q 1=K 2=V
  const int bn  = (blockIdx.y & 7) * BN;
  const u16* W = sel == 0 ? wq : sel == 1 ? wk : wv;
  const float* bias = sel == 0 ? bq : sel == 1 ? bk : bv;
  const int K = DM, N = DM;

  const int srow  = tid >> 3;
  const int sslot = (tid & 7) ^ (srow & 7);
  const size_t aoff = (size_t)(bm + srow) * K + sslot * 8;
  const size_t boff = (size_t)(bn + srow) * K + sslot * 8;

  f32x4 acc[4][4] = {};
  int cur = 0;

  auto STAGE = [&](int buf, int kt) {
    const u16* ga = A + aoff + kt * BK;
    const u16* gb = W + boff + kt * BK;
    u16* la = &smem[buf][0][wid * 512];
    u16* lb = &smem[buf][1][wid * 512];
#pragma unroll
    for (int i = 0; i < 4; ++i) {
      gld16(ga + (size_t)i * 32 * K, la + i * 2048);
      gld16(gb + (size_t)i * 32 * K, lb + i * 2048);
    }
  };

  STAGE(0, 0);
  __syncthreads();

  for (int kt = 0; kt < 16; ++kt) {
    if (kt + 1 < 16) STAGE(cur ^ 1, kt + 1);
    const u16* la = &smem[cur][0][0];
    const u16* lb = &smem[cur][1][0];
#pragma unroll
    for (int kk = 0; kk < 2; ++kk) {
      const int swz = ((kk * 4 + hi) ^ (r16 & 7)) * 8;
      bf16x8 af[4], bfr[4];
#pragma unroll
      for (int i = 0; i < 4; ++i)
        af[i] = *(const bf16x8*)&la[(wm * 64 + i * 16 + r16) * 64 + swz];
#pragma unroll
      for (int j = 0; j < 4; ++j)
        bfr[j] = *(const bf16x8*)&lb[(wn * 64 + j * 16 + r16) * 64 + swz];
      __builtin_amdgcn_s_setprio(1);
#pragma unroll
      for (int i = 0; i < 4; ++i)
#pragma unroll
        for (int j = 0; j < 4; ++j)
          acc[i][j] = __builtin_amdgcn_mfma_f32_16x16x32_bf16(af[i], bfr[j],
                                                              acc[i][j], 0, 0, 0);
      __builtin_amdgcn_s_setprio(0);
    }
    __syncthreads();
    cur ^= 1;
  }

#pragma unroll
  for (int i = 0; i < 4; ++i) {
#pragma unroll
    for (int j = 0; j < 4; ++j) {
      const int c  = bn + wn * 64 + j * 16 + r16;
      const int r0 = bm + wm * 64 + i * 16 + hi * 4;
      const float bvv = bias[c];
#pragma unroll
      for (int rr = 0; rr < 4; ++rr) {
        const int r = r0 + rr;
        const float v = acc[i][j][rr] + bvv;
        if (sel == 0) {
          qo[(size_t)r * N + c] = f2bf(v * QSCALE);
        } else if (sel == 1) {
          ko[(size_t)r * N + c] = f2bf(v);
        } else {
          const int b = r >> 11, s = r & 2047;
          const int hh = c >> 6, dk = c & 63;
          vo[((size_t)((b * NH + hh) * DKH + dk)) * SL + s] = f2bf(v);
        }
      }
    }
  }
}

// ---------------- flash attention, swapped-operand 32x32 MFMA (R8-exact) ----
__global__ __launch_bounds__(256, 2)
void attn(const u16* __restrict__ q, const u16* __restrict__ k,
          const u16* __restrict__ vt, u16* __restrict__ ctx) {
  __shared__ u16 kl[2][64 * 64];   // [kv][dk] swizzled
  __shared__ u16 vl[2][64 * 64];   // [dk][kv] swizzled

  const int tid = threadIdx.x;
  const int lane = tid & 63, wid = tid >> 6;
  const int l31 = lane & 31, h = lane >> 5;
  const int rs = l31 & 7;
  const int bh = blockIdx.x, b = bh >> 4, hh = bh & 15;
  const int qg = blockIdx.y * 128 + wid * 32 + l31;   // this lane's q row

  bf16x8 qf[4];
#pragma unroll
  for (int kq = 0; kq < 4; ++kq)
    qf[kq] = *(const bf16x8*)(q + (size_t)(b * SL + qg) * DM + hh * DKH +
                              kq * 16 + h * 8);

  f32x16 o0 = {}, o1 = {};          // O^T accum: dk rows [0,32) and [32,64)
  float mrun = -1e30f, lrun = 0.f;

  const int srow  = tid >> 3;
  const int sslot = (tid & 7) ^ (srow & 7);

  auto STAGE = [&](int buf, int t) {
    const u16* gk = k + (size_t)(b * SL + t * 64 + srow) * DM + hh * DKH + sslot * 8;
    const u16* gv = vt + (size_t)(bh * DKH + srow) * SL + t * 64 + sslot * 8;
    u16* lk = &kl[buf][wid * 512];
    u16* lv = &vl[buf][wid * 512];
#pragma unroll
    for (int i = 0; i < 2; ++i) {
      gld16(gk + (size_t)i * 32 * DM, lk + i * 2048);
      gld16(gv + (size_t)i * 32 * SL, lv + i * 2048);
    }
  };

  auto TILE = [&](int buf) {
    const u16* lk = kl[buf];
    const u16* lv = vl[buf];
    f32x16 s0 = {}, s1 = {};   // S^T fragments: kv rows [0,32) and [32,64)
    __builtin_amdgcn_s_setprio(1);
#pragma unroll
    for (int kq = 0; kq < 4; ++kq) {
      const int ls = 2 * kq + h;
      bf16x8 k0 = *(const bf16x8*)&lk[l31 * 64 + ((ls ^ rs) * 8)];
      bf16x8 k1 = *(const bf16x8*)&lk[(l31 + 32) * 64 + ((ls ^ rs) * 8)];
      s0 = __builtin_amdgcn_mfma_f32_32x32x16_bf16(k0, qf[kq], s0, 0, 0, 0);
      s1 = __builtin_amdgcn_mfma_f32_32x32x16_bf16(k1, qf[kq], s1, 0, 0, 0);
    }
    __builtin_amdgcn_s_setprio(0);

    float mx = fmaxf(s0[0], s0[1]);
#pragma unroll
    for (int r = 2; r < 16; ++r) mx = fmaxf(mx, s0[r]);
#pragma unroll
    for (int r = 0; r < 16; ++r) mx = fmaxf(mx, s1[r]);
    {
      float ta = mx, tb = mx;
      asm volatile("v_permlane32_swap_b32 %0, %1" : "+v"(ta), "+v"(tb));
      mx = fmaxf(ta, tb);
    }
    if (!__all(mx <= mrun + 11.0f)) {
      const float mn = fmaxf(mrun, mx);
      const float al = __builtin_amdgcn_exp2f(mrun - mn);
      mrun = mn;
      lrun *= al;
      o0 *= al; o1 *= al;
    }
    float lsum = 0.f;
#pragma unroll
    for (int r = 0; r < 16; ++r) {
      s0[r] = __builtin_amdgcn_exp2f(s0[r] - mrun); lsum += s0[r];
    }
#pragma unroll
    for (int r = 0; r < 16; ++r) {
      s1[r] = __builtin_amdgcn_exp2f(s1[r] - mrun); lsum += s1[r];
    }
    lrun += lsum;

    u32 A[16];
#pragma unroll
    for (int r = 0; r < 8; ++r)
      asm("v_cvt_pk_bf16_f32 %0, %1, %2"
          : "=v"(A[r]) : "v"(s0[2 * r]), "v"(s0[2 * r + 1]));
#pragma unroll
    for (int r = 0; r < 8; ++r)
      asm("v_cvt_pk_bf16_f32 %0, %1, %2"
          : "=v"(A[8 + r]) : "v"(s1[2 * r]), "v"(s1[2 * r + 1]));
#pragma unroll
    for (int g = 0; g < 4; ++g) {
      asm volatile("v_permlane32_swap_b32 %0, %1" : "+v"(A[4 * g + 0]), "+v"(A[4 * g + 2]));
      asm volatile("v_permlane32_swap_b32 %0, %1" : "+v"(A[4 * g + 1]), "+v"(A[4 * g + 3]));
    }

    __builtin_amdgcn_s_setprio(1);
#pragma unroll
    for (int ks = 0; ks < 4; ++ks) {
      union { u32 u[4]; bf16x8 hv; } pb;
      pb.u[0] = A[4 * ks + 0]; pb.u[1] = A[4 * ks + 1];
      pb.u[2] = A[4 * ks + 2]; pb.u[3] = A[4 * ks + 3];
      const int ls = 2 * ks + h;
      bf16x8 v0 = *(const bf16x8*)&lv[l31 * 64 + ((ls ^ rs) * 8)];
      bf16x8 v1 = *(const bf16x8*)&lv[(l31 + 32) * 64 + ((ls ^ rs) * 8)];
      o0 = __builtin_amdgcn_mfma_f32_32x32x16_bf16(v0, pb.hv, o0, 0, 0, 0);
      o1 = __builtin_amdgcn_mfma_f32_32x32x16_bf16(v1, pb.hv, o1, 0, 0, 0);
    }
    __builtin_amdgcn_s_setprio(0);
  };

  STAGE(0, 0);
  __syncthreads();
  int cur = 0;
  for (int t = 0; t < SL / 64; ++t) {
    if (t + 1 < SL / 64) STAGE(cur ^ 1, t + 1);
    TILE(cur);
    __syncthreads();
    cur ^= 1;
  }

  float ta = lrun, tb = lrun;
  asm volatile("v_permlane32_swap_b32 %0, %1" : "+v"(ta), "+v"(tb));
  const float rl = 1.f / (ta + tb);
  const size_t obase = (size_t)(b * SL + qg) * DM + hh * DKH;
#pragma unroll
  for (int df = 0; df < 2; ++df) {
#pragma unroll
    for (int r2 = 0; r2 < 4; ++r2) {
      const int dk0 = 8 * r2 + 4 * h + 32 * df;
      ushort4 st;
      if (df == 0) {
        st.x = f2bf(o0[4 * r2 + 0] * rl); st.y = f2bf(o0[4 * r2 + 1] * rl);
        st.z = f2bf(o0[4 * r2 + 2] * rl); st.w = f2bf(o0[4 * r2 + 3] * rl);
      } else {
        st.x = f2bf(o1[4 * r2 + 0] * rl); st.y = f2bf(o1[4 * r2 + 1] * rl);
        st.z = f2bf(o1[4 * r2 + 2] * rl); st.w = f2bf(o1[4 * r2 + 3] * rl);
      }
      *(ushort4*)(ctx + obase + dk0) = st;
    }
  }
}

// ---------------- LayerNorm over last dim (1024), one block per row ---------
template <int INBF>
__global__ __launch_bounds__(256)
void ln_k(const void* __restrict__ inp, const float* __restrict__ g,
          const float* __restrict__ be, float* __restrict__ outf,
          u16* __restrict__ outb) {
  const int row = blockIdx.x;
  const int tid = threadIdx.x;
  float4 x4;
  if (INBF) {
    ushort4 h4 = ((const ushort4*)((const u16*)inp + (size_t)row * DM))[tid];
    x4.x = bf2f(h4.x); x4.y = bf2f(h4.y); x4.z = bf2f(h4.z); x4.w = bf2f(h4.w);
  } else {
    x4 = ((const float4*)((const float*)inp + (size_t)row * DM))[tid];
  }
  float s  = x4.x + x4.y + x4.z + x4.w;
  float s2 = x4.x * x4.x + x4.y * x4.y + x4.z * x4.z + x4.w * x4.w;
#pragma unroll
  for (int d = 1; d < 64; d <<= 1) {
    s  += __shfl_xor(s, d);
    s2 += __shfl_xor(s2, d);
  }
  __shared__ float ps[8];
  const int wid = tid >> 6, lane = tid & 63;
  if (lane == 0) { ps[wid] = s; ps[wid + 4] = s2; }
  __syncthreads();
  const float S  = ps[0] + ps[1] + ps[2] + ps[3];
  const float S2 = ps[4] + ps[5] + ps[6] + ps[7];
  const float mu = S * (1.f / DM);
  const float var = S2 * (1.f / DM) - mu * mu;
  const float rstd = 1.f / sqrtf(var + 1e-5f);
  const float4 gv = ((const float4*)g)[tid];
  const float4 bv = ((const float4*)be)[tid];
  float4 o;
  o.x = (x4.x - mu) * rstd * gv.x + bv.x;
  o.y = (x4.y - mu) * rstd * gv.y + bv.y;
  o.z = (x4.z - mu) * rstd * gv.z + bv.z;
  o.w = (x4.w - mu) * rstd * gv.w + bv.w;
  if (outf) ((float4*)(outf + (size_t)row * DM))[tid] = o;
  if (outb) {
    ushort4 ob = { f2bf(o.x), f2bf(o.y), f2bf(o.z), f2bf(o.w) };
    ((ushort4*)(outb + (size_t)row * DM))[tid] = ob;
  }
}

// ---------------------------------------------------------------------------
extern "C" void kernel_launch(void* const* d_in, const int* in_sizes, int n_in,
                              void* d_out, int out_size, void* d_ws, size_t ws_size,
                              hipStream_t stream) {
  const float* x   = (const float*)d_in[0];
  const float* wq  = (const float*)d_in[1];
  const float* bq  = (const float*)d_in[2];
  const float* wk  = (const float*)d_in[3];
  const float* bk  = (const float*)d_in[4];
  const float* wv  = (const float*)d_in[5];
  const float* bv  = (const float*)d_in[6];
  const float* wo  = (const float*)d_in[7];
  const float* bo  = (const float*)d_in[8];
  const float* g1  = (const float*)d_in[9];
  const float* be1 = (const float*)d_in[10];
  const float* w1  = (const float*)d_in[11];
  const float* b1  = (const float*)d_in[12];
  const float* w2  = (const float*)d_in[13];
  const float* b2  = (const float*)d_in[14];
  const float* g2  = (const float*)d_in[15];
  const float* be2 = (const float*)d_in[16];

  if (ws_size < ((size_t)80 << 20)) return;  // need 80 MiB of scratch

  char* ws = (char*)d_ws;
  u16*  xb   = (u16*)(ws);                      // 8M  [0,8)
  u16*  wqb  = (u16*)(ws + ((size_t)8  << 20)); // 2M
  u16*  wkb  = (u16*)(ws + ((size_t)10 << 20));
  u16*  wvb  = (u16*)(ws + ((size_t)12 << 20));
  u16*  wob  = (u16*)(ws + ((size_t)14 << 20));
  u16*  w1b  = (u16*)(ws + ((size_t)16 << 20)); // 8M
  u16*  w2b  = (u16*)(ws + ((size_t)24 << 20)); // 8M
  u16*  qbuf = (u16*)(ws + ((size_t)32 << 20)); // 8M
  u16*  kbuf = (u16*)(ws + ((size_t)40 << 20)); // 8M
  u16*  vtb  = (u16*)(ws + ((size_t)48 << 20)); // 8M
  u16*  ctx  = (u16*)(ws + ((size_t)56 << 20)); // 8M
  u16*  oresb = (u16*)(ws + ((size_t)64 << 20)); // 8M bf16 (o-proj + x)
  u16*  ffb   = (u16*)(ws + ((size_t)72 << 20)); // 8M bf16 (ff2 + attn_out)
  u16*  aob  = xb;    // alias: attn_out bf16 over xb (dead after QKV+O-proj)
  u16*  hb   = qbuf;  // alias: FFN hidden (32M) over q/k/vt/ctx (dead)

  float* out = (float*)d_out;
  dim3 blk(256);

  cvt_all<<<2048, blk, 0, stream>>>(x, wq, wk, wv, wo, w1, w2,
                                    xb, wqb, wkb, wvb, wob, w1b, w2b);
  gemm_qkv<<<dim3(32, 24), blk, 0, stream>>>(xb, wqb, wkb, wvb, bq, bk, bv,
                                             qbuf, kbuf, vtb);
  attn<<<dim3(32, 16), blk, 0, stream>>>(qbuf, kbuf, vtb, ctx);
  gemm_bt<3><<<dim3(32, 8), blk, 0, stream>>>(ctx, wob, bo, xb, oresb,
                                              NTOK, DM, DM);
  ln_k<1><<<4096, blk, 0, stream>>>(oresb, g1, be1, nullptr, aob);
  gemm_bt<4><<<dim3(32, 32), blk, 0, stream>>>(aob, w1b, b1, nullptr,
                                               hb, NTOK, DFF, DM);
  gemm_bt<3><<<dim3(32, 8), blk, 0, stream>>>(hb, w2b, b2, aob, ffb,
                                              NTOK, DM, DFF);
  ln_k<1><<<4096, blk, 0, stream>>>(ffb, g2, be2, out, nullptr);
}